// Round 12
// baseline (254.349 us; speedup 1.0000x reference)
//
#include <hip/hip_runtime.h>
#include <hip/hip_bf16.h>

#define NEG_SLOPE 0.2f

// ---------------------------------------------------------------------------
// GAT 2-layer, N=100k, E=3.2M (+self-loops handled analytically per node).
//
// R12: revert scatter grid to 256 blocks (R11's 128 regressed: scatter is
// LDS-atomic/issue-bound per CU, not write-amp-bound) and restructure the
// sort to count once instead of three times:
//   scatter_count (256x1024): count chunk in LDS, dump 2048 counts -> percnt
//   scan_bucket   (8x256):    per-bucket serial scan over 256 blocks:
//                             percnt -> per-(block,bucket) exclusive prefix,
//                             bucket totals -> gcnt (plain stores, no atomics)
//   scan_init     (1x512):    gcnt -> gbase exclusive scan (+ consts)
//   scatter_write (256x1024): basel = gbase + percnt staged in LDS, then
//                             single write pass (per-edge LDS cnt atomic only)
// Eliminates: bucket_hist kernel (25.6MB read + 3.2M LDS atomics + 131K
// global atomics), scatter phase-1 re-count (3.2M LDS atomics), gcnt memset.
//
// Aggregation unchanged (R8/R10 win): rank-round plain-RMW wave-private LDS
// accumulation, row stride 9, 512-thread blocks, next-pair prefetch.
//
// Layer 1 collapses because IN==1 (h1 = x*W1 is rank-1); softmax without
// max-subtraction (|logit| <~ 30; verified R2-R11 absmax 9.8e-4).
//
// ws layout (4B units):
//   [0..15]      consts | [16..2063] gcnt | [2064..4111] gbase
//   [4112..6159] gcursor (mid/fallback path only)
//   [+N] als2 | [+N] ald2 | [+8N] h2 | [+E] pairs | [+524288] percnt (new)
// Guards: N <= 131072. Tiers: new (needs ~18.9MB) -> R10-style (16.8MB) ->
// R2 atomic fallback.
// ---------------------------------------------------------------------------

// ---------------- new sort path ----------------

__global__ void scatter_count(const int* __restrict__ ei, int* __restrict__ percnt,
                              int E) {
    __shared__ int cnt[2048];
    int t = threadIdx.x;                       // 1024 threads
    int chunk = (E + gridDim.x - 1) / gridDim.x;
    int lo = blockIdx.x * chunk;
    int hi = min(E, lo + chunk);
    const int* dei = ei + E;
    for (int i = t; i < 2048; i += 1024) cnt[i] = 0;
    __syncthreads();
    bool vec = ((E & 3) == 0);
    int lo4 = (lo + 3) & ~3;
    int end4 = hi & ~3;
    if (vec && end4 > lo4) {
        for (int e = lo + t; e < lo4; e += 1024)
            atomicAdd(&cnt[dei[e] >> 6], 1);
        const int4* dei4 = (const int4*)dei;
        for (int v = (lo4 >> 2) + t; v < (end4 >> 2); v += 1024) {
            int4 d = dei4[v];
            atomicAdd(&cnt[d.x >> 6], 1);
            atomicAdd(&cnt[d.y >> 6], 1);
            atomicAdd(&cnt[d.z >> 6], 1);
            atomicAdd(&cnt[d.w >> 6], 1);
        }
        for (int e = end4 + t; e < hi; e += 1024)
            atomicAdd(&cnt[dei[e] >> 6], 1);
    } else {
        for (int e = lo + t; e < hi; e += 1024)
            atomicAdd(&cnt[dei[e] >> 6], 1);
    }
    __syncthreads();
    int* myp = percnt + blockIdx.x * 2048;
    for (int i = t; i < 2048; i += 1024) myp[i] = cnt[i];
}

// 2048 threads total; thread owns bucket bk: serial exclusive scan over the
// NBLK per-block counts (coalesced across threads), totals -> gcnt.
__global__ void scan_bucket(int* __restrict__ percnt, int* __restrict__ gcnt,
                            int NBLK) {
    int bk = blockIdx.x * blockDim.x + threadIdx.x;
    if (bk >= 2048) return;
    int run = 0;
    for (int blk = 0; blk < NBLK; ++blk) {
        int c = percnt[blk * 2048 + bk];
        percnt[blk * 2048 + bk] = run;
        run += c;
    }
    gcnt[bk] = run;
}

// single block, 512 threads; consts + exclusive scan of 2048 bucket counts.
__global__ void scan_init(const int* __restrict__ gcnt,
                          int* __restrict__ gbase, int* __restrict__ gcursor,
                          const float* __restrict__ W1,
                          const float* __restrict__ as1,
                          const float* __restrict__ ad1,
                          float* __restrict__ consts) {
    __shared__ int buf[512];
    int t = threadIdx.x;
    if (t < 8) {
        int h = t & 3;
        const float* a = (t < 4) ? as1 : ad1;
        float s = 0.f;
        #pragma unroll
        for (int c = 0; c < 8; ++c)
            s += W1[h * 8 + c] * a[h * 8 + c];
        consts[t] = s;
    }
    int c0 = gcnt[t * 4], c1 = gcnt[t * 4 + 1], c2 = gcnt[t * 4 + 2], c3 = gcnt[t * 4 + 3];
    int sum = c0 + c1 + c2 + c3;
    buf[t] = sum;
    __syncthreads();
    for (int o = 1; o < 512; o <<= 1) {
        int add = (t >= o) ? buf[t - o] : 0;
        __syncthreads();
        buf[t] += add;
        __syncthreads();
    }
    int base = buf[t] - sum;                       // exclusive
    gbase[t * 4] = base;     gcursor[t * 4] = base;     base += c0;
    gbase[t * 4 + 1] = base; gcursor[t * 4 + 1] = base; base += c1;
    gbase[t * 4 + 2] = base; gcursor[t * 4 + 2] = base; base += c2;
    gbase[t * 4 + 3] = base; gcursor[t * 4 + 3] = base;
}

__global__ void scatter_write(const int* __restrict__ ei,
                              const int* __restrict__ gbase,
                              const int* __restrict__ percnt,
                              unsigned int* __restrict__ pairs, int E) {
    __shared__ int cnt[2048];
    __shared__ int basel[2048];
    int t = threadIdx.x;                       // 1024 threads
    int chunk = (E + gridDim.x - 1) / gridDim.x;
    int lo = blockIdx.x * chunk;
    int hi = min(E, lo + chunk);
    const int* dei = ei + E;
    const int* myp = percnt + blockIdx.x * 2048;
    for (int i = t; i < 2048; i += 1024) {
        cnt[i] = 0;
        basel[i] = gbase[i] + myp[i];
    }
    __syncthreads();
    bool vec = ((E & 3) == 0);
    int lo4 = (lo + 3) & ~3;
    int end4 = hi & ~3;
    if (vec && end4 > lo4) {
        for (int e = lo + t; e < lo4; e += 1024) {
            int s = ei[e], d = dei[e];
            int bk = d >> 6;
            int loc = atomicAdd(&cnt[bk], 1);
            pairs[basel[bk] + loc] = (unsigned)s | ((unsigned)(d & 63) << 17);
        }
        const int4* sei4 = (const int4*)ei;
        const int4* dei4 = (const int4*)dei;
        for (int v = (lo4 >> 2) + t; v < (end4 >> 2); v += 1024) {
            int4 sv = sei4[v];
            int4 dv = dei4[v];
            int bk0 = dv.x >> 6, bk1 = dv.y >> 6, bk2 = dv.z >> 6, bk3 = dv.w >> 6;
            int l0 = atomicAdd(&cnt[bk0], 1);
            pairs[basel[bk0] + l0] = (unsigned)sv.x | ((unsigned)(dv.x & 63) << 17);
            int l1 = atomicAdd(&cnt[bk1], 1);
            pairs[basel[bk1] + l1] = (unsigned)sv.y | ((unsigned)(dv.y & 63) << 17);
            int l2 = atomicAdd(&cnt[bk2], 1);
            pairs[basel[bk2] + l2] = (unsigned)sv.z | ((unsigned)(dv.z & 63) << 17);
            int l3 = atomicAdd(&cnt[bk3], 1);
            pairs[basel[bk3] + l3] = (unsigned)sv.w | ((unsigned)(dv.w & 63) << 17);
        }
        for (int e = end4 + t; e < hi; e += 1024) {
            int s = ei[e], d = dei[e];
            int bk = d >> 6;
            int loc = atomicAdd(&cnt[bk], 1);
            pairs[basel[bk] + loc] = (unsigned)s | ((unsigned)(d & 63) << 17);
        }
    } else {
        for (int e = lo + t; e < hi; e += 1024) {
            int s = ei[e], d = dei[e];
            int bk = d >> 6;
            int loc = atomicAdd(&cnt[bk], 1);
            pairs[basel[bk] + loc] = (unsigned)s | ((unsigned)(d & 63) << 17);
        }
    }
}

// ---------------- mid path (R10) sort kernels ----------------

__global__ void bucket_hist(const int* __restrict__ ei, int* __restrict__ gcnt, int E) {
    __shared__ int cnt[2048];
    int t = threadIdx.x;
    for (int i = t; i < 2048; i += 256) cnt[i] = 0;
    __syncthreads();
    const int* dei = ei + E;
    int gid = blockIdx.x * 256 + t;
    int gstride = gridDim.x * 256;
    if ((E & 3) == 0) {
        const int4* dei4 = (const int4*)dei;
        int E4 = E >> 2;
        for (int v = gid; v < E4; v += gstride) {
            int4 d = dei4[v];
            atomicAdd(&cnt[d.x >> 6], 1);
            atomicAdd(&cnt[d.y >> 6], 1);
            atomicAdd(&cnt[d.z >> 6], 1);
            atomicAdd(&cnt[d.w >> 6], 1);
        }
    } else {
        for (int e = gid; e < E; e += gstride)
            atomicAdd(&cnt[dei[e] >> 6], 1);
    }
    __syncthreads();
    for (int i = t; i < 2048; i += 256) {
        int c = cnt[i];
        if (c) atomicAdd(&gcnt[i], c);
    }
}

__global__ void bucket_scatter(const int* __restrict__ ei, int* __restrict__ gcursor,
                               unsigned int* __restrict__ pairs, int E) {
    __shared__ int cnt[2048];
    __shared__ int basel[2048];
    int t = threadIdx.x;
    int chunk = (E + gridDim.x - 1) / gridDim.x;
    int lo = blockIdx.x * chunk;
    int hi = min(E, lo + chunk);
    const int* dei = ei + E;
    for (int i = t; i < 2048; i += 1024) cnt[i] = 0;
    __syncthreads();
    for (int e = lo + t; e < hi; e += 1024)
        atomicAdd(&cnt[dei[e] >> 6], 1);
    __syncthreads();
    for (int i = t; i < 2048; i += 1024) {
        int c = cnt[i];
        basel[i] = c ? atomicAdd(&gcursor[i], c) : 0;
        cnt[i] = 0;
    }
    __syncthreads();
    for (int e = lo + t; e < hi; e += 1024) {
        int s = ei[e], d = dei[e];
        int bk = d >> 6;
        int loc = atomicAdd(&cnt[bk], 1);
        pairs[basel[bk] + loc] = (unsigned)s | ((unsigned)(d & 63) << 17);
    }
}

// ---------------- aggregation (unchanged from R10) ----------------

__global__ void l1_comb(const float* __restrict__ x,
                        const int* __restrict__ gbase, const int* __restrict__ gcnt,
                        const unsigned int* __restrict__ pairs,
                        const float* __restrict__ consts,
                        const float* __restrict__ W1, const float* __restrict__ b1,
                        const float* __restrict__ W2,
                        const float* __restrict__ as2, const float* __restrict__ ad2,
                        float* __restrict__ h2, float* __restrict__ als2,
                        float* __restrict__ ald2, int N) {
    __shared__ float R[8 * 64 * 9];   // wave-private rows: [0..3]=s1,[4..7]=t1, pad 1
    __shared__ float xl[64];
    int t = threadIdx.x;
    int lane = t & 63;
    int bk = blockIdx.x;
    int node0 = bk << 6;
    int nw = min(64, N - node0);
    for (int i = t; i < 8 * 64 * 9; i += 512) R[i] = 0.f;
    if (t < nw) xl[t] = x[node0 + t];
    float S[4], D[4];
    #pragma unroll
    for (int h = 0; h < 4; ++h) { S[h] = consts[h]; D[h] = consts[4 + h]; }
    __syncthreads();
    float* wreg = &R[(t >> 6) * 576];
    int b = gbase[bk];
    int hi = b + gcnt[bk];
    int i = b + t;
    unsigned p = (i < hi) ? pairs[i] : 0u;
    while (i < hi) {
        int inx = i + 512;
        unsigned pn = 0u;
        if (inx < hi) pn = pairs[inx];          // prefetch next iteration's pair
        int src = (int)(p & 131071u);
        int ld  = (int)(p >> 17);
        float xs = x[src];
        float xd = xl[ld];
        float w[4];
        #pragma unroll
        for (int h = 0; h < 4; ++h) {
            float v = xs * S[h] + xd * D[h];
            v = (v > 0.f) ? v : NEG_SLOPE * v;
            w[h] = __expf(v);
        }
        unsigned long long mask = ~0ull;
        #pragma unroll
        for (int bit = 0; bit < 6; ++bit) {
            unsigned long long bb = __ballot((ld >> bit) & 1);
            mask &= ((ld >> bit) & 1) ? bb : ~bb;
        }
        mask &= __ballot(1);
        int rank = __popcll(mask & ((1ull << lane) - 1ull));
        float* row = &wreg[ld * 9];
        for (int r = 0; r < 64; ++r) {
            if (__ballot(rank == r) == 0ull) break;
            if (rank == r) {
                row[0] += w[0]; row[1] += w[1]; row[2] += w[2]; row[3] += w[3];
                row[4] = fmaf(w[0], xs, row[4]); row[5] = fmaf(w[1], xs, row[5]);
                row[6] = fmaf(w[2], xs, row[6]); row[7] = fmaf(w[3], xs, row[7]);
            }
        }
        p = pn; i = inx;
    }
    __syncthreads();
    if (t < nw) {
        int n = node0 + t;
        float xn = xl[t];
        float o[8];
        #pragma unroll
        for (int c = 0; c < 8; ++c) o[c] = 0.f;
        #pragma unroll
        for (int h = 0; h < 4; ++h) {
            float v = xn * (S[h] + D[h]);           // self-loop term
            v = (v > 0.f) ? v : NEG_SLOPE * v;
            float ww = __expf(v);
            float s1 = ww, t1 = ww * xn;
            #pragma unroll
            for (int r = 0; r < 8; ++r) {
                s1 += R[r * 576 + t * 9 + h];
                t1 += R[r * 576 + t * 9 + 4 + h];
            }
            float tt = t1 / s1;
            #pragma unroll
            for (int c = 0; c < 8; ++c) {
                float rr = fmaxf(tt * W1[h * 8 + c] + b1[h * 8 + c], 0.f);
                #pragma unroll
                for (int c2 = 0; c2 < 8; ++c2) o[c2] += rr * W2[(h * 8 + c) * 8 + c2];
            }
        }
        float as = 0.f, ad = 0.f;
        #pragma unroll
        for (int c = 0; c < 8; ++c) { as += o[c] * as2[c]; ad += o[c] * ad2[c]; }
        float4* hv = (float4*)&h2[(size_t)n * 8];
        hv[0] = make_float4(o[0], o[1], o[2], o[3]);
        hv[1] = make_float4(o[4], o[5], o[6], o[7]);
        als2[n] = as;
        ald2[n] = ad;
    }
}

__global__ void l2_comb(const int* __restrict__ gbase, const int* __restrict__ gcnt,
                        const unsigned int* __restrict__ pairs,
                        const float* __restrict__ als2, const float* __restrict__ ald2,
                        const float* __restrict__ h2, const float* __restrict__ b2,
                        float* __restrict__ out, int N) {
    __shared__ float R[8 * 64 * 9];   // wave-private rows: [0]=s2, [1..8]=acc
    __shared__ float adl[64];
    int t = threadIdx.x;
    int lane = t & 63;
    int bk = blockIdx.x;
    int node0 = bk << 6;
    int nw = min(64, N - node0);
    for (int i = t; i < 8 * 64 * 9; i += 512) R[i] = 0.f;
    if (t < nw) adl[t] = ald2[node0 + t];
    __syncthreads();
    float* wreg = &R[(t >> 6) * 576];
    int b = gbase[bk];
    int hi = b + gcnt[bk];
    int i = b + t;
    unsigned p = (i < hi) ? pairs[i] : 0u;
    while (i < hi) {
        int inx = i + 512;
        unsigned pn = 0u;
        if (inx < hi) pn = pairs[inx];          // prefetch
        int src = (int)(p & 131071u);
        int ld  = (int)(p >> 17);
        float a = als2[src];
        const float4* hv = (const float4*)&h2[(size_t)src * 8];
        float4 ha = hv[0], hb = hv[1];
        float v = a + adl[ld];
        v = (v > 0.f) ? v : NEG_SLOPE * v;
        float w = __expf(v);
        unsigned long long mask = ~0ull;
        #pragma unroll
        for (int bit = 0; bit < 6; ++bit) {
            unsigned long long bb = __ballot((ld >> bit) & 1);
            mask &= ((ld >> bit) & 1) ? bb : ~bb;
        }
        mask &= __ballot(1);
        int rank = __popcll(mask & ((1ull << lane) - 1ull));
        float* row = &wreg[ld * 9];
        for (int r = 0; r < 64; ++r) {
            if (__ballot(rank == r) == 0ull) break;
            if (rank == r) {
                row[0] += w;
                row[1] = fmaf(w, ha.x, row[1]); row[2] = fmaf(w, ha.y, row[2]);
                row[3] = fmaf(w, ha.z, row[3]); row[4] = fmaf(w, ha.w, row[4]);
                row[5] = fmaf(w, hb.x, row[5]); row[6] = fmaf(w, hb.y, row[6]);
                row[7] = fmaf(w, hb.z, row[7]); row[8] = fmaf(w, hb.w, row[8]);
            }
        }
        p = pn; i = inx;
    }
    __syncthreads();
    if (t < nw) {
        int n = node0 + t;
        float v = als2[n] + adl[t];               // self-loop
        v = (v > 0.f) ? v : NEG_SLOPE * v;
        float ww = __expf(v);
        const float4* hv = (const float4*)&h2[(size_t)n * 8];
        float4 ha0 = hv[0], hb0 = hv[1];
        float acc[9];
        #pragma unroll
        for (int c = 0; c < 9; ++c) {
            float s = 0.f;
            #pragma unroll
            for (int r = 0; r < 8; ++r) s += R[r * 576 + t * 9 + c];
            acc[c] = s;
        }
        float s2 = acc[0] + ww;
        float inv = 1.f / s2;
        float4* ov = (float4*)&out[(size_t)n * 8];
        ov[0] = make_float4((acc[1] + ww * ha0.x) * inv + b2[0],
                            (acc[2] + ww * ha0.y) * inv + b2[1],
                            (acc[3] + ww * ha0.z) * inv + b2[2],
                            (acc[4] + ww * ha0.w) * inv + b2[3]);
        ov[1] = make_float4((acc[5] + ww * hb0.x) * inv + b2[4],
                            (acc[6] + ww * hb0.y) * inv + b2[5],
                            (acc[7] + ww * hb0.z) * inv + b2[6],
                            (acc[8] + ww * hb0.w) * inv + b2[7]);
    }
}

// ---------------- fallback path (R2, atomic-based; known-correct) ----------------

__global__ void prep_consts(const float* __restrict__ W1,
                            const float* __restrict__ as1,
                            const float* __restrict__ ad1,
                            float* __restrict__ consts) {
    int t = threadIdx.x;
    if (t >= 8) return;
    int h = t & 3;
    const float* a = (t < 4) ? as1 : ad1;
    float s = 0.f;
    #pragma unroll
    for (int c = 0; c < 8; ++c)
        s += W1[h * 8 + c] * a[h * 8 + c];
    consts[t] = s;
}

__global__ void edge_pass1(const int* __restrict__ ei, const float* __restrict__ x,
                           const float* __restrict__ consts,
                           float* __restrict__ s1, float* __restrict__ t1, int E, int N) {
    int e = blockIdx.x * blockDim.x + threadIdx.x;
    if (e >= E + N) return;
    int src, dst;
    if (e < E) { src = ei[e]; dst = ei[E + e]; }
    else       { src = dst = e - E; }
    float xs = x[src], xd = x[dst];
    #pragma unroll
    for (int h = 0; h < 4; ++h) {
        float v = xs * consts[h] + xd * consts[4 + h];
        v = (v > 0.f) ? v : NEG_SLOPE * v;
        float w = __expf(v);
        atomicAdd(&s1[dst * 4 + h], w);
        atomicAdd(&t1[dst * 4 + h], w * xs);
    }
}

__global__ void node_mid(const float* __restrict__ s1, const float* __restrict__ t1,
                         const float* __restrict__ W1, const float* __restrict__ b1,
                         const float* __restrict__ W2,
                         const float* __restrict__ as2, const float* __restrict__ ad2,
                         float* __restrict__ h2, float* __restrict__ als2,
                         float* __restrict__ ald2, int N) {
    int n = blockIdx.x * blockDim.x + threadIdx.x;
    if (n >= N) return;
    float o[8];
    #pragma unroll
    for (int c = 0; c < 8; ++c) o[c] = 0.f;
    #pragma unroll
    for (int h = 0; h < 4; ++h) {
        float t = t1[n * 4 + h] / s1[n * 4 + h];
        #pragma unroll
        for (int c = 0; c < 8; ++c) {
            float r = fmaxf(t * W1[h * 8 + c] + b1[h * 8 + c], 0.f);
            #pragma unroll
            for (int c2 = 0; c2 < 8; ++c2) o[c2] += r * W2[(h * 8 + c) * 8 + c2];
        }
    }
    float as = 0.f, ad = 0.f;
    #pragma unroll
    for (int c = 0; c < 8; ++c) { h2[n * 8 + c] = o[c]; as += o[c] * as2[c]; ad += o[c] * ad2[c]; }
    als2[n] = as; ald2[n] = ad;
}

__global__ void edge_pass2(const int* __restrict__ ei, const float* __restrict__ als2,
                           const float* __restrict__ ald2, const float* __restrict__ h2,
                           float* __restrict__ s2, float* __restrict__ acc2, int E, int N) {
    int e = blockIdx.x * blockDim.x + threadIdx.x;
    if (e >= E + N) return;
    int src, dst;
    if (e < E) { src = ei[e]; dst = ei[E + e]; }
    else       { src = dst = e - E; }
    float v = als2[src] + ald2[dst];
    v = (v > 0.f) ? v : NEG_SLOPE * v;
    float w = __expf(v);
    atomicAdd(&s2[dst], w);
    const float4* hs = (const float4*)&h2[src * 8];
    float4 a = hs[0], bq = hs[1];
    float* acc = &acc2[dst * 8];
    atomicAdd(&acc[0], w * a.x);  atomicAdd(&acc[1], w * a.y);
    atomicAdd(&acc[2], w * a.z);  atomicAdd(&acc[3], w * a.w);
    atomicAdd(&acc[4], w * bq.x); atomicAdd(&acc[5], w * bq.y);
    atomicAdd(&acc[6], w * bq.z); atomicAdd(&acc[7], w * bq.w);
}

__global__ void node_out(const float* __restrict__ s2, const float* __restrict__ acc2,
                         const float* __restrict__ b2, float* __restrict__ out, int N) {
    int i = blockIdx.x * blockDim.x + threadIdx.x;
    if (i >= N * 8) return;
    out[i] = acc2[i] / s2[i >> 3] + b2[i & 7];
}

// ---------------------------------------------------------------------------

extern "C" void kernel_launch(void* const* d_in, const int* in_sizes, int n_in,
                              void* d_out, int out_size, void* d_ws, size_t ws_size,
                              hipStream_t stream) {
    const float* x   = (const float*)d_in[0];
    const int*   ei  = (const int*)d_in[1];
    const float* W1  = (const float*)d_in[2];
    const float* as1 = (const float*)d_in[3];
    const float* ad1 = (const float*)d_in[4];
    const float* b1  = (const float*)d_in[5];
    const float* W2  = (const float*)d_in[6];
    const float* as2 = (const float*)d_in[7];
    const float* ad2 = (const float*)d_in[8];
    const float* b2  = (const float*)d_in[9];
    float* out = (float*)d_out;

    const int N = in_sizes[0];          // 100000
    const int E = in_sizes[1] / 2;      // 3200000
    const int NBK = (N + 63) >> 6;      // 1563 buckets of 64 nodes
    const int SBLK = 256;               // sort blocks

    float* ws = (float*)d_ws;
    size_t base_units = (size_t)(16 + 3 * 2048 + 10 * (size_t)N + (size_t)E);
    size_t need_old = base_units * sizeof(float);
    size_t need_new = (base_units + (size_t)SBLK * 2048) * sizeof(float);

    float*    consts  = ws;                          // 16
    int*      gcnt    = (int*)(ws + 16);             // 2048
    int*      gbase   = gcnt + 2048;                 // 2048
    int*      gcursor = gbase + 2048;                // 2048
    float*    als2    = ws + 16 + 3 * 2048;          // N
    float*    ald2    = als2 + N;                    // N
    float*    h2      = ald2 + N;                    // 8N
    unsigned* pairs   = (unsigned*)(h2 + 8 * (size_t)N);  // E
    int*      percnt  = (int*)(pairs + (size_t)E);   // SBLK*2048 (new path)

    if (N <= 131072 && ws_size >= need_new) {
        // ---- new path: count-once sort ----
        scatter_count<<<SBLK, 1024, 0, stream>>>(ei, percnt, E);
        scan_bucket<<<8, 256, 0, stream>>>(percnt, gcnt, SBLK);
        scan_init<<<1, 512, 0, stream>>>(gcnt, gbase, gcursor, W1, as1, ad1, consts);
        scatter_write<<<SBLK, 1024, 0, stream>>>(ei, gbase, percnt, pairs, E);
        l1_comb<<<NBK, 512, 0, stream>>>(x, gbase, gcnt, pairs, consts,
                                         W1, b1, W2, as2, ad2, h2, als2, ald2, N);
        l2_comb<<<NBK, 512, 0, stream>>>(gbase, gcnt, pairs, als2, ald2, h2, b2, out, N);
    } else if (N <= 131072 && ws_size >= need_old) {
        // ---- mid path: R10 structure (hist + 2-phase scatter, 256 blocks) ----
        hipMemsetAsync(gcnt, 0, 2048 * sizeof(int), stream);
        bucket_hist<<<256, 256, 0, stream>>>(ei, gcnt, E);
        scan_init<<<1, 512, 0, stream>>>(gcnt, gbase, gcursor, W1, as1, ad1, consts);
        bucket_scatter<<<256, 1024, 0, stream>>>(ei, gcursor, pairs, E);
        l1_comb<<<NBK, 512, 0, stream>>>(x, gbase, gcnt, pairs, consts,
                                         W1, b1, W2, as2, ad2, h2, als2, ald2, N);
        l2_comb<<<NBK, 512, 0, stream>>>(gbase, gcnt, pairs, als2, ald2, h2, b2, out, N);
    } else {
        // ---- fallback: R2 atomic path (10.8 MB ws, known-correct) ----
        float* s1   = ws + 16;
        float* t1   = s1 + 4 * (size_t)N;
        float* h2f  = t1 + 4 * (size_t)N;
        float* als2f= h2f + 8 * (size_t)N;
        float* ald2f= als2f + (size_t)N;
        float* s2   = ald2f + (size_t)N;
        float* acc2 = s2 + (size_t)N;

        hipMemsetAsync(ws, 0, (16 + 8 * (size_t)N) * sizeof(float), stream);
        hipMemsetAsync(s2, 0, 9 * (size_t)N * sizeof(float), stream);
        prep_consts<<<1, 64, 0, stream>>>(W1, as1, ad1, consts);
        int total = E + N;
        edge_pass1<<<(total + 255) / 256, 256, 0, stream>>>(ei, x, consts, s1, t1, E, N);
        node_mid<<<(N + 255) / 256, 256, 0, stream>>>(s1, t1, W1, b1, W2, as2, ad2, h2f, als2f, ald2f, N);
        edge_pass2<<<(total + 255) / 256, 256, 0, stream>>>(ei, als2f, ald2f, h2f, s2, acc2, E, N);
        node_out<<<(N * 8 + 255) / 256, 256, 0, stream>>>(s2, acc2, b2, out, N);
    }
}

// Round 13
// 202.023 us; speedup vs baseline: 1.2590x; 1.2590x over previous
//
#include <hip/hip_runtime.h>
#include <hip/hip_bf16.h>

#define NEG_SLOPE 0.2f

// ---------------------------------------------------------------------------
// GAT 2-layer, N=100k, E=3.2M (+self-loops handled analytically per node).
//
// R13: fix R12's scan_bucket latency blunder (71us: 2048 threads, 8 blocks,
// 256-iteration dependent L2 chain each). New scan: ONE WAVE PER BUCKET
// (2048 waves = 512 blocks): lane l owns blocks 4l..4l+3 (serial depth 4),
// in-lane prefix + 6-step __shfl_up wave exclusive scan, write back.
// Count-once sort pipeline otherwise kept from R12:
//   scatter_count (256x1024): count chunk in LDS -> percnt (no re-count)
//   scan_bucket   (512x256):  percnt -> per-(block,bucket) exclusive prefix
//   scan_init     (1x512):    gcnt -> gbase (+ consts)
//   scatter_write (256x1024): basel staged in LDS, single write pass
// Aggregation unchanged (R8/R10 win): rank-round plain-RMW wave-private LDS
// accumulation, row stride 9, 512-thread blocks, next-pair prefetch.
//
// Layer 1 collapses because IN==1 (h1 = x*W1 is rank-1); softmax without
// max-subtraction (|logit| <~ 30; verified R2-R12 absmax 9.8e-4).
//
// ws layout (4B units):
//   [0..15] consts | [16..2063] gcnt | [2064..4111] gbase
//   [4112..6159] gcursor (mid/fallback only)
//   [+N] als2 | [+N] ald2 | [+8N] h2 | [+E] pairs | [+524288] percnt
// Guards: N <= 131072. Tiers: new (~18.9MB) -> R10-style (16.8MB) -> R2.
// ---------------------------------------------------------------------------

// ---------------- count-once sort path ----------------

__global__ void scatter_count(const int* __restrict__ ei, int* __restrict__ percnt,
                              int E) {
    __shared__ int cnt[2048];
    int t = threadIdx.x;                       // 1024 threads
    int chunk = (E + gridDim.x - 1) / gridDim.x;
    int lo = blockIdx.x * chunk;
    int hi = min(E, lo + chunk);
    const int* dei = ei + E;
    for (int i = t; i < 2048; i += 1024) cnt[i] = 0;
    __syncthreads();
    bool vec = ((E & 3) == 0);
    int lo4 = (lo + 3) & ~3;
    int end4 = hi & ~3;
    if (vec && end4 > lo4) {
        for (int e = lo + t; e < lo4; e += 1024)
            atomicAdd(&cnt[dei[e] >> 6], 1);
        const int4* dei4 = (const int4*)dei;
        for (int v = (lo4 >> 2) + t; v < (end4 >> 2); v += 1024) {
            int4 d = dei4[v];
            atomicAdd(&cnt[d.x >> 6], 1);
            atomicAdd(&cnt[d.y >> 6], 1);
            atomicAdd(&cnt[d.z >> 6], 1);
            atomicAdd(&cnt[d.w >> 6], 1);
        }
        for (int e = end4 + t; e < hi; e += 1024)
            atomicAdd(&cnt[dei[e] >> 6], 1);
    } else {
        for (int e = lo + t; e < hi; e += 1024)
            atomicAdd(&cnt[dei[e] >> 6], 1);
    }
    __syncthreads();
    int* myp = percnt + blockIdx.x * 2048;
    for (int i = t; i < 2048; i += 1024) myp[i] = cnt[i];
}

// One wave per bucket (2048 waves): lane owns 4 blocks, wave shfl-scan.
// Requires NBLK <= 256.
__global__ void scan_bucket(int* __restrict__ percnt, int* __restrict__ gcnt,
                            int NBLK) {
    int wid = (blockIdx.x * blockDim.x + threadIdx.x) >> 6;  // bucket id
    int lane = threadIdx.x & 63;
    if (wid >= 2048) return;
    int base = lane * 4;
    int c0 = (base + 0 < NBLK) ? percnt[(size_t)(base + 0) * 2048 + wid] : 0;
    int c1 = (base + 1 < NBLK) ? percnt[(size_t)(base + 1) * 2048 + wid] : 0;
    int c2 = (base + 2 < NBLK) ? percnt[(size_t)(base + 2) * 2048 + wid] : 0;
    int c3 = (base + 3 < NBLK) ? percnt[(size_t)(base + 3) * 2048 + wid] : 0;
    int p1 = c0, p2 = c0 + c1, p3 = c0 + c1 + c2;
    int lsum = p3 + c3;
    int v = lsum;
    #pragma unroll
    for (int o = 1; o < 64; o <<= 1) {
        int u = __shfl_up(v, o, 64);
        if (lane >= o) v += u;
    }
    int excl = v - lsum;                       // wave-exclusive prefix
    if (base + 0 < NBLK) percnt[(size_t)(base + 0) * 2048 + wid] = excl;
    if (base + 1 < NBLK) percnt[(size_t)(base + 1) * 2048 + wid] = excl + p1;
    if (base + 2 < NBLK) percnt[(size_t)(base + 2) * 2048 + wid] = excl + p2;
    if (base + 3 < NBLK) percnt[(size_t)(base + 3) * 2048 + wid] = excl + p3;
    if (lane == 63) gcnt[wid] = excl + lsum;
}

// single block, 512 threads; consts + exclusive scan of 2048 bucket counts.
__global__ void scan_init(const int* __restrict__ gcnt,
                          int* __restrict__ gbase, int* __restrict__ gcursor,
                          const float* __restrict__ W1,
                          const float* __restrict__ as1,
                          const float* __restrict__ ad1,
                          float* __restrict__ consts) {
    __shared__ int buf[512];
    int t = threadIdx.x;
    if (t < 8) {
        int h = t & 3;
        const float* a = (t < 4) ? as1 : ad1;
        float s = 0.f;
        #pragma unroll
        for (int c = 0; c < 8; ++c)
            s += W1[h * 8 + c] * a[h * 8 + c];
        consts[t] = s;
    }
    int c0 = gcnt[t * 4], c1 = gcnt[t * 4 + 1], c2 = gcnt[t * 4 + 2], c3 = gcnt[t * 4 + 3];
    int sum = c0 + c1 + c2 + c3;
    buf[t] = sum;
    __syncthreads();
    for (int o = 1; o < 512; o <<= 1) {
        int add = (t >= o) ? buf[t - o] : 0;
        __syncthreads();
        buf[t] += add;
        __syncthreads();
    }
    int base = buf[t] - sum;                       // exclusive
    gbase[t * 4] = base;     gcursor[t * 4] = base;     base += c0;
    gbase[t * 4 + 1] = base; gcursor[t * 4 + 1] = base; base += c1;
    gbase[t * 4 + 2] = base; gcursor[t * 4 + 2] = base; base += c2;
    gbase[t * 4 + 3] = base; gcursor[t * 4 + 3] = base;
}

__global__ void scatter_write(const int* __restrict__ ei,
                              const int* __restrict__ gbase,
                              const int* __restrict__ percnt,
                              unsigned int* __restrict__ pairs, int E) {
    __shared__ int cnt[2048];
    __shared__ int basel[2048];
    int t = threadIdx.x;                       // 1024 threads
    int chunk = (E + gridDim.x - 1) / gridDim.x;
    int lo = blockIdx.x * chunk;
    int hi = min(E, lo + chunk);
    const int* dei = ei + E;
    const int* myp = percnt + blockIdx.x * 2048;
    for (int i = t; i < 2048; i += 1024) {
        cnt[i] = 0;
        basel[i] = gbase[i] + myp[i];
    }
    __syncthreads();
    bool vec = ((E & 3) == 0);
    int lo4 = (lo + 3) & ~3;
    int end4 = hi & ~3;
    if (vec && end4 > lo4) {
        for (int e = lo + t; e < lo4; e += 1024) {
            int s = ei[e], d = dei[e];
            int bk = d >> 6;
            int loc = atomicAdd(&cnt[bk], 1);
            pairs[basel[bk] + loc] = (unsigned)s | ((unsigned)(d & 63) << 17);
        }
        const int4* sei4 = (const int4*)ei;
        const int4* dei4 = (const int4*)dei;
        for (int v = (lo4 >> 2) + t; v < (end4 >> 2); v += 1024) {
            int4 sv = sei4[v];
            int4 dv = dei4[v];
            int bk0 = dv.x >> 6, bk1 = dv.y >> 6, bk2 = dv.z >> 6, bk3 = dv.w >> 6;
            int l0 = atomicAdd(&cnt[bk0], 1);
            pairs[basel[bk0] + l0] = (unsigned)sv.x | ((unsigned)(dv.x & 63) << 17);
            int l1 = atomicAdd(&cnt[bk1], 1);
            pairs[basel[bk1] + l1] = (unsigned)sv.y | ((unsigned)(dv.y & 63) << 17);
            int l2 = atomicAdd(&cnt[bk2], 1);
            pairs[basel[bk2] + l2] = (unsigned)sv.z | ((unsigned)(dv.z & 63) << 17);
            int l3 = atomicAdd(&cnt[bk3], 1);
            pairs[basel[bk3] + l3] = (unsigned)sv.w | ((unsigned)(dv.w & 63) << 17);
        }
        for (int e = end4 + t; e < hi; e += 1024) {
            int s = ei[e], d = dei[e];
            int bk = d >> 6;
            int loc = atomicAdd(&cnt[bk], 1);
            pairs[basel[bk] + loc] = (unsigned)s | ((unsigned)(d & 63) << 17);
        }
    } else {
        for (int e = lo + t; e < hi; e += 1024) {
            int s = ei[e], d = dei[e];
            int bk = d >> 6;
            int loc = atomicAdd(&cnt[bk], 1);
            pairs[basel[bk] + loc] = (unsigned)s | ((unsigned)(d & 63) << 17);
        }
    }
}

// ---------------- mid path (R10) sort kernels ----------------

__global__ void bucket_hist(const int* __restrict__ ei, int* __restrict__ gcnt, int E) {
    __shared__ int cnt[2048];
    int t = threadIdx.x;
    for (int i = t; i < 2048; i += 256) cnt[i] = 0;
    __syncthreads();
    const int* dei = ei + E;
    int gid = blockIdx.x * 256 + t;
    int gstride = gridDim.x * 256;
    if ((E & 3) == 0) {
        const int4* dei4 = (const int4*)dei;
        int E4 = E >> 2;
        for (int v = gid; v < E4; v += gstride) {
            int4 d = dei4[v];
            atomicAdd(&cnt[d.x >> 6], 1);
            atomicAdd(&cnt[d.y >> 6], 1);
            atomicAdd(&cnt[d.z >> 6], 1);
            atomicAdd(&cnt[d.w >> 6], 1);
        }
    } else {
        for (int e = gid; e < E; e += gstride)
            atomicAdd(&cnt[dei[e] >> 6], 1);
    }
    __syncthreads();
    for (int i = t; i < 2048; i += 256) {
        int c = cnt[i];
        if (c) atomicAdd(&gcnt[i], c);
    }
}

__global__ void bucket_scatter(const int* __restrict__ ei, int* __restrict__ gcursor,
                               unsigned int* __restrict__ pairs, int E) {
    __shared__ int cnt[2048];
    __shared__ int basel[2048];
    int t = threadIdx.x;
    int chunk = (E + gridDim.x - 1) / gridDim.x;
    int lo = blockIdx.x * chunk;
    int hi = min(E, lo + chunk);
    const int* dei = ei + E;
    for (int i = t; i < 2048; i += 1024) cnt[i] = 0;
    __syncthreads();
    for (int e = lo + t; e < hi; e += 1024)
        atomicAdd(&cnt[dei[e] >> 6], 1);
    __syncthreads();
    for (int i = t; i < 2048; i += 1024) {
        int c = cnt[i];
        basel[i] = c ? atomicAdd(&gcursor[i], c) : 0;
        cnt[i] = 0;
    }
    __syncthreads();
    for (int e = lo + t; e < hi; e += 1024) {
        int s = ei[e], d = dei[e];
        int bk = d >> 6;
        int loc = atomicAdd(&cnt[bk], 1);
        pairs[basel[bk] + loc] = (unsigned)s | ((unsigned)(d & 63) << 17);
    }
}

// ---------------- aggregation (unchanged from R10) ----------------

__global__ void l1_comb(const float* __restrict__ x,
                        const int* __restrict__ gbase, const int* __restrict__ gcnt,
                        const unsigned int* __restrict__ pairs,
                        const float* __restrict__ consts,
                        const float* __restrict__ W1, const float* __restrict__ b1,
                        const float* __restrict__ W2,
                        const float* __restrict__ as2, const float* __restrict__ ad2,
                        float* __restrict__ h2, float* __restrict__ als2,
                        float* __restrict__ ald2, int N) {
    __shared__ float R[8 * 64 * 9];   // wave-private rows: [0..3]=s1,[4..7]=t1, pad 1
    __shared__ float xl[64];
    int t = threadIdx.x;
    int lane = t & 63;
    int bk = blockIdx.x;
    int node0 = bk << 6;
    int nw = min(64, N - node0);
    for (int i = t; i < 8 * 64 * 9; i += 512) R[i] = 0.f;
    if (t < nw) xl[t] = x[node0 + t];
    float S[4], D[4];
    #pragma unroll
    for (int h = 0; h < 4; ++h) { S[h] = consts[h]; D[h] = consts[4 + h]; }
    __syncthreads();
    float* wreg = &R[(t >> 6) * 576];
    int b = gbase[bk];
    int hi = b + gcnt[bk];
    int i = b + t;
    unsigned p = (i < hi) ? pairs[i] : 0u;
    while (i < hi) {
        int inx = i + 512;
        unsigned pn = 0u;
        if (inx < hi) pn = pairs[inx];          // prefetch next iteration's pair
        int src = (int)(p & 131071u);
        int ld  = (int)(p >> 17);
        float xs = x[src];
        float xd = xl[ld];
        float w[4];
        #pragma unroll
        for (int h = 0; h < 4; ++h) {
            float v = xs * S[h] + xd * D[h];
            v = (v > 0.f) ? v : NEG_SLOPE * v;
            w[h] = __expf(v);
        }
        unsigned long long mask = ~0ull;
        #pragma unroll
        for (int bit = 0; bit < 6; ++bit) {
            unsigned long long bb = __ballot((ld >> bit) & 1);
            mask &= ((ld >> bit) & 1) ? bb : ~bb;
        }
        mask &= __ballot(1);
        int rank = __popcll(mask & ((1ull << lane) - 1ull));
        float* row = &wreg[ld * 9];
        for (int r = 0; r < 64; ++r) {
            if (__ballot(rank == r) == 0ull) break;
            if (rank == r) {
                row[0] += w[0]; row[1] += w[1]; row[2] += w[2]; row[3] += w[3];
                row[4] = fmaf(w[0], xs, row[4]); row[5] = fmaf(w[1], xs, row[5]);
                row[6] = fmaf(w[2], xs, row[6]); row[7] = fmaf(w[3], xs, row[7]);
            }
        }
        p = pn; i = inx;
    }
    __syncthreads();
    if (t < nw) {
        int n = node0 + t;
        float xn = xl[t];
        float o[8];
        #pragma unroll
        for (int c = 0; c < 8; ++c) o[c] = 0.f;
        #pragma unroll
        for (int h = 0; h < 4; ++h) {
            float v = xn * (S[h] + D[h]);           // self-loop term
            v = (v > 0.f) ? v : NEG_SLOPE * v;
            float ww = __expf(v);
            float s1 = ww, t1 = ww * xn;
            #pragma unroll
            for (int r = 0; r < 8; ++r) {
                s1 += R[r * 576 + t * 9 + h];
                t1 += R[r * 576 + t * 9 + 4 + h];
            }
            float tt = t1 / s1;
            #pragma unroll
            for (int c = 0; c < 8; ++c) {
                float rr = fmaxf(tt * W1[h * 8 + c] + b1[h * 8 + c], 0.f);
                #pragma unroll
                for (int c2 = 0; c2 < 8; ++c2) o[c2] += rr * W2[(h * 8 + c) * 8 + c2];
            }
        }
        float as = 0.f, ad = 0.f;
        #pragma unroll
        for (int c = 0; c < 8; ++c) { as += o[c] * as2[c]; ad += o[c] * ad2[c]; }
        float4* hv = (float4*)&h2[(size_t)n * 8];
        hv[0] = make_float4(o[0], o[1], o[2], o[3]);
        hv[1] = make_float4(o[4], o[5], o[6], o[7]);
        als2[n] = as;
        ald2[n] = ad;
    }
}

__global__ void l2_comb(const int* __restrict__ gbase, const int* __restrict__ gcnt,
                        const unsigned int* __restrict__ pairs,
                        const float* __restrict__ als2, const float* __restrict__ ald2,
                        const float* __restrict__ h2, const float* __restrict__ b2,
                        float* __restrict__ out, int N) {
    __shared__ float R[8 * 64 * 9];   // wave-private rows: [0]=s2, [1..8]=acc
    __shared__ float adl[64];
    int t = threadIdx.x;
    int lane = t & 63;
    int bk = blockIdx.x;
    int node0 = bk << 6;
    int nw = min(64, N - node0);
    for (int i = t; i < 8 * 64 * 9; i += 512) R[i] = 0.f;
    if (t < nw) adl[t] = ald2[node0 + t];
    __syncthreads();
    float* wreg = &R[(t >> 6) * 576];
    int b = gbase[bk];
    int hi = b + gcnt[bk];
    int i = b + t;
    unsigned p = (i < hi) ? pairs[i] : 0u;
    while (i < hi) {
        int inx = i + 512;
        unsigned pn = 0u;
        if (inx < hi) pn = pairs[inx];          // prefetch
        int src = (int)(p & 131071u);
        int ld  = (int)(p >> 17);
        float a = als2[src];
        const float4* hv = (const float4*)&h2[(size_t)src * 8];
        float4 ha = hv[0], hb = hv[1];
        float v = a + adl[ld];
        v = (v > 0.f) ? v : NEG_SLOPE * v;
        float w = __expf(v);
        unsigned long long mask = ~0ull;
        #pragma unroll
        for (int bit = 0; bit < 6; ++bit) {
            unsigned long long bb = __ballot((ld >> bit) & 1);
            mask &= ((ld >> bit) & 1) ? bb : ~bb;
        }
        mask &= __ballot(1);
        int rank = __popcll(mask & ((1ull << lane) - 1ull));
        float* row = &wreg[ld * 9];
        for (int r = 0; r < 64; ++r) {
            if (__ballot(rank == r) == 0ull) break;
            if (rank == r) {
                row[0] += w;
                row[1] = fmaf(w, ha.x, row[1]); row[2] = fmaf(w, ha.y, row[2]);
                row[3] = fmaf(w, ha.z, row[3]); row[4] = fmaf(w, ha.w, row[4]);
                row[5] = fmaf(w, hb.x, row[5]); row[6] = fmaf(w, hb.y, row[6]);
                row[7] = fmaf(w, hb.z, row[7]); row[8] = fmaf(w, hb.w, row[8]);
            }
        }
        p = pn; i = inx;
    }
    __syncthreads();
    if (t < nw) {
        int n = node0 + t;
        float v = als2[n] + adl[t];               // self-loop
        v = (v > 0.f) ? v : NEG_SLOPE * v;
        float ww = __expf(v);
        const float4* hv = (const float4*)&h2[(size_t)n * 8];
        float4 ha0 = hv[0], hb0 = hv[1];
        float acc[9];
        #pragma unroll
        for (int c = 0; c < 9; ++c) {
            float s = 0.f;
            #pragma unroll
            for (int r = 0; r < 8; ++r) s += R[r * 576 + t * 9 + c];
            acc[c] = s;
        }
        float s2 = acc[0] + ww;
        float inv = 1.f / s2;
        float4* ov = (float4*)&out[(size_t)n * 8];
        ov[0] = make_float4((acc[1] + ww * ha0.x) * inv + b2[0],
                            (acc[2] + ww * ha0.y) * inv + b2[1],
                            (acc[3] + ww * ha0.z) * inv + b2[2],
                            (acc[4] + ww * ha0.w) * inv + b2[3]);
        ov[1] = make_float4((acc[5] + ww * hb0.x) * inv + b2[4],
                            (acc[6] + ww * hb0.y) * inv + b2[5],
                            (acc[7] + ww * hb0.z) * inv + b2[6],
                            (acc[8] + ww * hb0.w) * inv + b2[7]);
    }
}

// ---------------- fallback path (R2, atomic-based; known-correct) ----------------

__global__ void prep_consts(const float* __restrict__ W1,
                            const float* __restrict__ as1,
                            const float* __restrict__ ad1,
                            float* __restrict__ consts) {
    int t = threadIdx.x;
    if (t >= 8) return;
    int h = t & 3;
    const float* a = (t < 4) ? as1 : ad1;
    float s = 0.f;
    #pragma unroll
    for (int c = 0; c < 8; ++c)
        s += W1[h * 8 + c] * a[h * 8 + c];
    consts[t] = s;
}

__global__ void edge_pass1(const int* __restrict__ ei, const float* __restrict__ x,
                           const float* __restrict__ consts,
                           float* __restrict__ s1, float* __restrict__ t1, int E, int N) {
    int e = blockIdx.x * blockDim.x + threadIdx.x;
    if (e >= E + N) return;
    int src, dst;
    if (e < E) { src = ei[e]; dst = ei[E + e]; }
    else       { src = dst = e - E; }
    float xs = x[src], xd = x[dst];
    #pragma unroll
    for (int h = 0; h < 4; ++h) {
        float v = xs * consts[h] + xd * consts[4 + h];
        v = (v > 0.f) ? v : NEG_SLOPE * v;
        float w = __expf(v);
        atomicAdd(&s1[dst * 4 + h], w);
        atomicAdd(&t1[dst * 4 + h], w * xs);
    }
}

__global__ void node_mid(const float* __restrict__ s1, const float* __restrict__ t1,
                         const float* __restrict__ W1, const float* __restrict__ b1,
                         const float* __restrict__ W2,
                         const float* __restrict__ as2, const float* __restrict__ ad2,
                         float* __restrict__ h2, float* __restrict__ als2,
                         float* __restrict__ ald2, int N) {
    int n = blockIdx.x * blockDim.x + threadIdx.x;
    if (n >= N) return;
    float o[8];
    #pragma unroll
    for (int c = 0; c < 8; ++c) o[c] = 0.f;
    #pragma unroll
    for (int h = 0; h < 4; ++h) {
        float t = t1[n * 4 + h] / s1[n * 4 + h];
        #pragma unroll
        for (int c = 0; c < 8; ++c) {
            float r = fmaxf(t * W1[h * 8 + c] + b1[h * 8 + c], 0.f);
            #pragma unroll
            for (int c2 = 0; c2 < 8; ++c2) o[c2] += r * W2[(h * 8 + c) * 8 + c2];
        }
    }
    float as = 0.f, ad = 0.f;
    #pragma unroll
    for (int c = 0; c < 8; ++c) { h2[n * 8 + c] = o[c]; as += o[c] * as2[c]; ad += o[c] * ad2[c]; }
    als2[n] = as; ald2[n] = ad;
}

__global__ void edge_pass2(const int* __restrict__ ei, const float* __restrict__ als2,
                           const float* __restrict__ ald2, const float* __restrict__ h2,
                           float* __restrict__ s2, float* __restrict__ acc2, int E, int N) {
    int e = blockIdx.x * blockDim.x + threadIdx.x;
    if (e >= E + N) return;
    int src, dst;
    if (e < E) { src = ei[e]; dst = ei[E + e]; }
    else       { src = dst = e - E; }
    float v = als2[src] + ald2[dst];
    v = (v > 0.f) ? v : NEG_SLOPE * v;
    float w = __expf(v);
    atomicAdd(&s2[dst], w);
    const float4* hs = (const float4*)&h2[src * 8];
    float4 a = hs[0], bq = hs[1];
    float* acc = &acc2[dst * 8];
    atomicAdd(&acc[0], w * a.x);  atomicAdd(&acc[1], w * a.y);
    atomicAdd(&acc[2], w * a.z);  atomicAdd(&acc[3], w * a.w);
    atomicAdd(&acc[4], w * bq.x); atomicAdd(&acc[5], w * bq.y);
    atomicAdd(&acc[6], w * bq.z); atomicAdd(&acc[7], w * bq.w);
}

__global__ void node_out(const float* __restrict__ s2, const float* __restrict__ acc2,
                         const float* __restrict__ b2, float* __restrict__ out, int N) {
    int i = blockIdx.x * blockDim.x + threadIdx.x;
    if (i >= N * 8) return;
    out[i] = acc2[i] / s2[i >> 3] + b2[i & 7];
}

// ---------------------------------------------------------------------------

extern "C" void kernel_launch(void* const* d_in, const int* in_sizes, int n_in,
                              void* d_out, int out_size, void* d_ws, size_t ws_size,
                              hipStream_t stream) {
    const float* x   = (const float*)d_in[0];
    const int*   ei  = (const int*)d_in[1];
    const float* W1  = (const float*)d_in[2];
    const float* as1 = (const float*)d_in[3];
    const float* ad1 = (const float*)d_in[4];
    const float* b1  = (const float*)d_in[5];
    const float* W2  = (const float*)d_in[6];
    const float* as2 = (const float*)d_in[7];
    const float* ad2 = (const float*)d_in[8];
    const float* b2  = (const float*)d_in[9];
    float* out = (float*)d_out;

    const int N = in_sizes[0];          // 100000
    const int E = in_sizes[1] / 2;      // 3200000
    const int NBK = (N + 63) >> 6;      // 1563 buckets of 64 nodes
    const int SBLK = 256;               // sort blocks (<=256 for scan_bucket)

    float* ws = (float*)d_ws;
    size_t base_units = (size_t)(16 + 3 * 2048 + 10 * (size_t)N + (size_t)E);
    size_t need_old = base_units * sizeof(float);
    size_t need_new = (base_units + (size_t)SBLK * 2048) * sizeof(float);

    float*    consts  = ws;                          // 16
    int*      gcnt    = (int*)(ws + 16);             // 2048
    int*      gbase   = gcnt + 2048;                 // 2048
    int*      gcursor = gbase + 2048;                // 2048
    float*    als2    = ws + 16 + 3 * 2048;          // N
    float*    ald2    = als2 + N;                    // N
    float*    h2      = ald2 + N;                    // 8N
    unsigned* pairs   = (unsigned*)(h2 + 8 * (size_t)N);  // E
    int*      percnt  = (int*)(pairs + (size_t)E);   // SBLK*2048 (new path)

    if (N <= 131072 && ws_size >= need_new) {
        // ---- count-once sort, wave-parallel scan ----
        scatter_count<<<SBLK, 1024, 0, stream>>>(ei, percnt, E);
        scan_bucket<<<512, 256, 0, stream>>>(percnt, gcnt, SBLK);
        scan_init<<<1, 512, 0, stream>>>(gcnt, gbase, gcursor, W1, as1, ad1, consts);
        scatter_write<<<SBLK, 1024, 0, stream>>>(ei, gbase, percnt, pairs, E);
        l1_comb<<<NBK, 512, 0, stream>>>(x, gbase, gcnt, pairs, consts,
                                         W1, b1, W2, as2, ad2, h2, als2, ald2, N);
        l2_comb<<<NBK, 512, 0, stream>>>(gbase, gcnt, pairs, als2, ald2, h2, b2, out, N);
    } else if (N <= 131072 && ws_size >= need_old) {
        // ---- mid path: R10 structure (hist + 2-phase scatter, 256 blocks) ----
        hipMemsetAsync(gcnt, 0, 2048 * sizeof(int), stream);
        bucket_hist<<<256, 256, 0, stream>>>(ei, gcnt, E);
        scan_init<<<1, 512, 0, stream>>>(gcnt, gbase, gcursor, W1, as1, ad1, consts);
        bucket_scatter<<<256, 1024, 0, stream>>>(ei, gcursor, pairs, E);
        l1_comb<<<NBK, 512, 0, stream>>>(x, gbase, gcnt, pairs, consts,
                                         W1, b1, W2, as2, ad2, h2, als2, ald2, N);
        l2_comb<<<NBK, 512, 0, stream>>>(gbase, gcnt, pairs, als2, ald2, h2, b2, out, N);
    } else {
        // ---- fallback: R2 atomic path (10.8 MB ws, known-correct) ----
        float* s1   = ws + 16;
        float* t1   = s1 + 4 * (size_t)N;
        float* h2f  = t1 + 4 * (size_t)N;
        float* als2f= h2f + 8 * (size_t)N;
        float* ald2f= als2f + (size_t)N;
        float* s2   = ald2f + (size_t)N;
        float* acc2 = s2 + (size_t)N;

        hipMemsetAsync(ws, 0, (16 + 8 * (size_t)N) * sizeof(float), stream);
        hipMemsetAsync(s2, 0, 9 * (size_t)N * sizeof(float), stream);
        prep_consts<<<1, 64, 0, stream>>>(W1, as1, ad1, consts);
        int total = E + N;
        edge_pass1<<<(total + 255) / 256, 256, 0, stream>>>(ei, x, consts, s1, t1, E, N);
        node_mid<<<(N + 255) / 256, 256, 0, stream>>>(s1, t1, W1, b1, W2, as2, ad2, h2f, als2f, ald2f, N);
        edge_pass2<<<(total + 255) / 256, 256, 0, stream>>>(ei, als2f, ald2f, h2f, s2, acc2, E, N);
        node_out<<<(N * 8 + 255) / 256, 256, 0, stream>>>(s2, acc2, b2, out, N);
    }
}